// Round 9
// baseline (248.416 us; speedup 1.0000x reference)
//
#include <hip/hip_runtime.h>
#include <hip/hip_bf16.h>
#include <math.h>

#define HCOLS 256          // H * C = 4 * 64, hidden width for all layers
#define NHEAD 4
#define CDIM  64
#define NEG_SLOPE 0.2f

typedef __attribute__((ext_vector_type(8))) short bf16x8;
typedef __attribute__((ext_vector_type(4))) float f32x4;

__device__ __forceinline__ float leaky(float v) { return v > 0.f ? v : v * NEG_SLOPE; }
__device__ __forceinline__ unsigned short f2bf(float f) {      // RNE
    unsigned u = __float_as_uint(f);
    u += 0x7fff + ((u >> 16) & 1);
    return (unsigned short)(u >> 16);
}

// expand uint4 (8 bf16) and fma into acc[8] with scalar a
__device__ __forceinline__ void fma8(float* acc, uint4 hv, float a) {
    acc[0] = fmaf(a, __uint_as_float(hv.x << 16),          acc[0]);
    acc[1] = fmaf(a, __uint_as_float(hv.x & 0xffff0000u),  acc[1]);
    acc[2] = fmaf(a, __uint_as_float(hv.y << 16),          acc[2]);
    acc[3] = fmaf(a, __uint_as_float(hv.y & 0xffff0000u),  acc[3]);
    acc[4] = fmaf(a, __uint_as_float(hv.z << 16),          acc[4]);
    acc[5] = fmaf(a, __uint_as_float(hv.z & 0xffff0000u),  acc[5]);
    acc[6] = fmaf(a, __uint_as_float(hv.w << 16),          acc[6]);
    acc[7] = fmaf(a, __uint_as_float(hv.w & 0xffff0000u),  acc[7]);
}

// ---------------------------------------------------------------- prep: zero deg + W transpose/convert
__global__ void prep_kernel(const float* __restrict__ W0, const float* __restrict__ W1,
                            const float* __restrict__ W2,
                            unsigned short* __restrict__ Wt0, unsigned short* __restrict__ Wt1,
                            unsigned short* __restrict__ Wt2,
                            int* __restrict__ deg, int n, int nzb) {
    int b = blockIdx.x;
    if (b < nzb) {
        int i = b * 256 + threadIdx.x;
        if (i < n) deg[i] = 0;
        return;
    }
    b -= nzb;
    int z = b >> 6;                      // 64 tiles per matrix
    int rem = b & 63;
    int bx = rem & 7, by = rem >> 3;
    const float* W = (z == 0) ? W0 : (z == 1) ? W1 : W2;
    unsigned short* Wt = (z == 0) ? Wt0 : (z == 1) ? Wt1 : Wt2;
    int K = (z == 0) ? 128 : 256;
    if (by * 32 >= K) return;
    __shared__ float t[32][33];
    int tx = threadIdx.x & 31, ty = threadIdx.x >> 5;   // 32 x 8
#pragma unroll
    for (int i = 0; i < 32; i += 8)
        t[ty + i][tx] = W[(by * 32 + ty + i) * HCOLS + bx * 32 + tx];
    __syncthreads();
#pragma unroll
    for (int i = 0; i < 32; i += 8)
        Wt[(size_t)(bx * 32 + ty + i) * K + by * 32 + tx] = f2bf(t[tx][ty + i]);
}

// ---------------------------------------------------------------- CSR build
__global__ void deg_kernel(const int* __restrict__ ei, int* __restrict__ deg,
                           int E, int Ep) {
    int e = blockIdx.x * 256 + threadIdx.x;
    if (e >= Ep) return;
    int d = (e < E) ? ei[E + e] : (e - E);
    atomicAdd(&deg[d], 1);
}

__global__ void scan_kernel(const int* __restrict__ deg, int* __restrict__ rowptr,
                            int* __restrict__ cursor, int n) {
    __shared__ int wsum[16];
    int tid = threadIdx.x;
    int lane = tid & 63, w = tid >> 6;
    int CH = (n + 1023) >> 10;
    int base = tid * CH;
    int s = 0;
    for (int k = 0; k < CH; ++k) {
        int i = base + k;
        s += (i < n) ? deg[i] : 0;
    }
    int incl = s;
#pragma unroll
    for (int d = 1; d < 64; d <<= 1) {
        int t = __shfl_up(incl, d, 64);
        if (lane >= d) incl += t;
    }
    if (lane == 63) wsum[w] = incl;
    __syncthreads();
    if (w == 0) {
        int v = (lane < 16) ? wsum[lane] : 0;
#pragma unroll
        for (int d = 1; d < 16; d <<= 1) {
            int t = __shfl_up(v, d, 64);
            if (lane >= d) v += t;
        }
        if (lane < 16) wsum[lane] = v;
    }
    __syncthreads();
    int woff = (w == 0) ? 0 : wsum[w - 1];
    int run = woff + incl - s;
    for (int k = 0; k < CH; ++k) {
        int i = base + k;
        if (i < n) { rowptr[i] = run; cursor[i] = run; run += deg[i]; }
    }
    if (tid == 1023) rowptr[n] = run;
}

__global__ void fill_kernel(const int* __restrict__ ei, int* __restrict__ cursor,
                            int* __restrict__ eidx, int E, int Ep) {
    int e = blockIdx.x * 256 + threadIdx.x;
    if (e >= Ep) return;
    int d = (e < E) ? ei[E + e] : (e - E);
    int pos = atomicAdd(&cursor[d], 1);
    eidx[pos] = e;
}

// ---------------------------------------------------------------- standalone MFMA GEMM (layer 0)
template <int K, bool SRC_F32>
__global__ void gemm_kernel(const void* __restrict__ Xv, const unsigned short* __restrict__ Wt,
                            unsigned short* __restrict__ Hout,
                            const float* __restrict__ As, const float* __restrict__ Ad,
                            float* __restrict__ esrc, float* __restrict__ edst,
                            int n) {
    constexpr int LDK = K + 16;
    __shared__ __align__(16) unsigned short a_sh[32 * LDK];
    int row0 = blockIdx.x * 32;
    int tid = threadIdx.x;

    constexpr int CH = 32 * K / 8;                  // 16B chunks
    for (int c = tid; c < CH; c += 256) {
        int r = c / (K / 8), kc = c % (K / 8);
        int row = row0 + r;
        uint4 pack;
        if (row < n) {
            if (SRC_F32) {
                const float* X = (const float*)Xv;
                float4 f0 = *reinterpret_cast<const float4*>(&X[(size_t)row * K + kc * 8]);
                float4 f1 = *reinterpret_cast<const float4*>(&X[(size_t)row * K + kc * 8 + 4]);
                pack.x = f2bf(f0.x) | ((unsigned)f2bf(f0.y) << 16);
                pack.y = f2bf(f0.z) | ((unsigned)f2bf(f0.w) << 16);
                pack.z = f2bf(f1.x) | ((unsigned)f2bf(f1.y) << 16);
                pack.w = f2bf(f1.z) | ((unsigned)f2bf(f1.w) << 16);
            } else {
                const uint4* X = (const uint4*)Xv;
                pack = X[((size_t)row * K + kc * 8) / 8];
            }
        } else {
            pack = make_uint4(0, 0, 0, 0);
        }
        *reinterpret_cast<uint4*>(&a_sh[r * LDK + kc * 8]) = pack;
    }
    __syncthreads();

    int lane = tid & 63;
    int w = tid >> 6;                              // wave == head
    int lr = lane & 15;
    int lk = (lane >> 4) * 8;

    f32x4 acc[2][4];
#pragma unroll
    for (int m = 0; m < 2; ++m)
#pragma unroll
        for (int nf = 0; nf < 4; ++nf) acc[m][nf] = (f32x4){0.f, 0.f, 0.f, 0.f};

    const unsigned short* wt = Wt + (size_t)(w * 64) * K;
#pragma unroll
    for (int ks = 0; ks < K / 32; ++ks) {
        bf16x8 a[2], b[4];
#pragma unroll
        for (int m = 0; m < 2; ++m)
            a[m] = *reinterpret_cast<const bf16x8*>(&a_sh[(16 * m + lr) * LDK + ks * 32 + lk]);
#pragma unroll
        for (int nf = 0; nf < 4; ++nf)
            b[nf] = *reinterpret_cast<const bf16x8*>(&wt[(size_t)(16 * nf + lr) * K + ks * 32 + lk]);
#pragma unroll
        for (int m = 0; m < 2; ++m)
#pragma unroll
            for (int nf = 0; nf < 4; ++nf)
                acc[m][nf] = __builtin_amdgcn_mfma_f32_16x16x32_bf16(a[m], b[nf], acc[m][nf], 0, 0, 0);
    }

    float as_v[4], ad_v[4];
#pragma unroll
    for (int nf = 0; nf < 4; ++nf) {
        as_v[nf] = As[w * 64 + 16 * nf + lr];
        ad_v[nf] = Ad[w * 64 + 16 * nf + lr];
    }
#pragma unroll
    for (int m = 0; m < 2; ++m) {
#pragma unroll
        for (int j = 0; j < 4; ++j) {
            int row_g = row0 + 16 * m + (lane >> 4) * 4 + j;
            bool ok = row_g < n;
#pragma unroll
            for (int nf = 0; nf < 4; ++nf) {
                if (ok) Hout[(size_t)row_g * HCOLS + w * 64 + 16 * nf + lr] = f2bf(acc[m][nf][j]);
            }
            float ps = acc[m][0][j] * as_v[0] + acc[m][1][j] * as_v[1] +
                       acc[m][2][j] * as_v[2] + acc[m][3][j] * as_v[3];
            float pd = acc[m][0][j] * ad_v[0] + acc[m][1][j] * ad_v[1] +
                       acc[m][2][j] * ad_v[2] + acc[m][3][j] * ad_v[3];
#pragma unroll
            for (int off = 1; off < 16; off <<= 1) {
                ps += __shfl_xor(ps, off, 64);
                pd += __shfl_xor(pd, off, 64);
            }
            if (lr == 0 && ok) {
                esrc[row_g * NHEAD + w] = ps;
                edst[row_g * NHEAD + w] = pd;
            }
        }
    }
}

// ================================================================ shared phase A+B body
// Works for any number of waves; wave handles 4 nodes (nidx = wave*4+g).
template <int LDX>
__device__ __forceinline__ void attn_phaseAB(
        const unsigned short* __restrict__ h,
        const float* __restrict__ esrc, const float* __restrict__ edst,
        const int* __restrict__ ei, const int* __restrict__ rowptr,
        const int* __restrict__ eidx, const float* __restrict__ bias,
        float* __restrict__ alpha,
        float (*aT)[64][NHEAD], int (*sArr)[64], unsigned short (*xs)[LDX],
        int nodeblk, int n, int E) {
    int tid = threadIdx.x;
    int wave = tid >> 6, lane = tid & 63;
    int g = lane >> 4, t = lane & 15;
    int nidx = wave * 4 + g;
    int node = nodeblk + nidx;
    bool gvalid = node < n;
    int s0 = 0, s1 = 0;
    if (gvalid) { s0 = rowptr[node]; s1 = rowptr[node + 1]; }
    int deg = s1 - s0;
    float4 ed = make_float4(0.f, 0.f, 0.f, 0.f);
    if (gvalid) ed = *reinterpret_cast<const float4*>(&edst[node * NHEAD]);

    // ---------- phase A: segment softmax (16-lane group per node)
    const float NEGINF = -3.4e38f;
    float4 lgc[4]; int sc[4], ec[4];
    int degc = deg < 64 ? deg : 64;
    int nch = (degc + 15) >> 4;
    float4 mx = make_float4(NEGINF, NEGINF, NEGINF, NEGINF);
#pragma unroll
    for (int c = 0; c < 4; ++c) {
        sc[c] = 0; ec[c] = 0;
        lgc[c] = make_float4(NEGINF, NEGINF, NEGINF, NEGINF);
        if (c < nch) {
            int i = s0 + c * 16 + t;
            bool v = i < s1;
            int e = v ? eidx[i] : 0;
            int s = v ? ((e < E) ? ei[e] : (e - E)) : 0;
            sc[c] = s; ec[c] = e;
            if (v) {
                float4 es = *reinterpret_cast<const float4*>(&esrc[s * NHEAD]);
                lgc[c].x = leaky(es.x + ed.x);
                lgc[c].y = leaky(es.y + ed.y);
                lgc[c].z = leaky(es.z + ed.z);
                lgc[c].w = leaky(es.w + ed.w);
            }
            mx.x = fmaxf(mx.x, lgc[c].x);
            mx.y = fmaxf(mx.y, lgc[c].y);
            mx.z = fmaxf(mx.z, lgc[c].z);
            mx.w = fmaxf(mx.w, lgc[c].w);
        }
    }
    for (int i = s0 + 64 + t; i < s1; i += 16) {   // rare: deg > 64
        int e = eidx[i];
        int s = (e < E) ? ei[e] : (e - E);
        float4 es = *reinterpret_cast<const float4*>(&esrc[s * NHEAD]);
        mx.x = fmaxf(mx.x, leaky(es.x + ed.x));
        mx.y = fmaxf(mx.y, leaky(es.y + ed.y));
        mx.z = fmaxf(mx.z, leaky(es.z + ed.z));
        mx.w = fmaxf(mx.w, leaky(es.w + ed.w));
    }
#pragma unroll
    for (int off = 1; off < 16; off <<= 1) {
        mx.x = fmaxf(mx.x, __shfl_xor(mx.x, off, 64));
        mx.y = fmaxf(mx.y, __shfl_xor(mx.y, off, 64));
        mx.z = fmaxf(mx.z, __shfl_xor(mx.z, off, 64));
        mx.w = fmaxf(mx.w, __shfl_xor(mx.w, off, 64));
    }
    float4 exc[4];
    float4 sm = make_float4(0.f, 0.f, 0.f, 0.f);
#pragma unroll
    for (int c = 0; c < 4; ++c) {
        exc[c] = make_float4(0.f, 0.f, 0.f, 0.f);
        if (c < nch) {
            exc[c].x = __expf(lgc[c].x - mx.x);   // invalid lanes: exp(-inf)=0
            exc[c].y = __expf(lgc[c].y - mx.y);
            exc[c].z = __expf(lgc[c].z - mx.z);
            exc[c].w = __expf(lgc[c].w - mx.w);
            sm.x += exc[c].x; sm.y += exc[c].y; sm.z += exc[c].z; sm.w += exc[c].w;
        }
    }
    for (int i = s0 + 64 + t; i < s1; i += 16) {   // rare
        int e = eidx[i];
        int s = (e < E) ? ei[e] : (e - E);
        float4 es = *reinterpret_cast<const float4*>(&esrc[s * NHEAD]);
        sm.x += __expf(leaky(es.x + ed.x) - mx.x);
        sm.y += __expf(leaky(es.y + ed.y) - mx.y);
        sm.z += __expf(leaky(es.z + ed.z) - mx.z);
        sm.w += __expf(leaky(es.w + ed.w) - mx.w);
    }
#pragma unroll
    for (int off = 1; off < 16; off <<= 1) {
        sm.x += __shfl_xor(sm.x, off, 64);
        sm.y += __shfl_xor(sm.y, off, 64);
        sm.z += __shfl_xor(sm.z, off, 64);
        sm.w += __shfl_xor(sm.w, off, 64);
    }
    float4 inv = make_float4(1.f / sm.x, 1.f / sm.y, 1.f / sm.z, 1.f / sm.w);
#pragma unroll
    for (int c = 0; c < 4; ++c) {
        if (c < nch) {
            float4 al4;
            al4.x = exc[c].x * inv.x; al4.y = exc[c].y * inv.y;
            al4.z = exc[c].z * inv.z; al4.w = exc[c].w * inv.w;
            int i = s0 + c * 16 + t;
            if (i < s1) *reinterpret_cast<float4*>(&alpha[(size_t)ec[c] * NHEAD]) = al4;
            *reinterpret_cast<float4*>(&aT[nidx][c * 16 + t][0]) = al4;  // 0 for invalid lanes
            sArr[nidx][c * 16 + t] = sc[c];
        }
    }
    for (int i = s0 + 64 + t; i < s1; i += 16) {   // rare
        int e = eidx[i];
        int s = (e < E) ? ei[e] : (e - E);
        float4 es = *reinterpret_cast<const float4*>(&esrc[s * NHEAD]);
        float4 av;
        av.x = __expf(leaky(es.x + ed.x) - mx.x) * inv.x;
        av.y = __expf(leaky(es.y + ed.y) - mx.y) * inv.y;
        av.z = __expf(leaky(es.z + ed.z) - mx.z) * inv.z;
        av.w = __expf(leaky(es.w + ed.w) - mx.w) * inv.w;
        *reinterpret_cast<float4*>(&alpha[(size_t)e * NHEAD]) = av;
    }
    if (__any(deg > 64)) __threadfence();

    asm volatile("s_waitcnt lgkmcnt(0)" ::: "memory");   // same-wave LDS write->read
    __builtin_amdgcn_sched_barrier(0);

    // ---------- phase B: x[node] = ELU(bias + sum_e alpha[e] * h[src(e)]) -> xs (bf16)
    int half = lane >> 5;                 // which edge of the pair
    int q = lane & 31;                    // 16B slot within 512B row
    int head = q >> 3;
    unsigned byteoff = (unsigned)q * 16u;
    const char* hb = (const char*)h;

    for (int g2 = 0; g2 < 4; ++g2) {
        int nl = wave * 4 + g2;
        int nd = nodeblk + nl;
        if (nd >= n) continue;
        int t0 = rowptr[nd], t1 = rowptr[nd + 1];
        int dg = t1 - t0;
        int m = dg < 64 ? dg : 64;
        int m2 = (m + 1) & ~1;
        const float* ap = &aT[nl][0][0] + head;
        const int* sp = &sArr[nl][0];
        float acc[8];
#pragma unroll
        for (int k = 0; k < 8; ++k) acc[k] = 0.f;
        int j = 0;
        for (; j + 4 <= m2; j += 4) {
            int jA = j + half, jB = j + 2 + half;
            int sA = sp[jA], sB = sp[jB];
            float aA = ap[jA * NHEAD], aB = ap[jB * NHEAD];
            uint4 hA = *reinterpret_cast<const uint4*>(hb + (((unsigned)sA) << 9) + byteoff);
            uint4 hB = *reinterpret_cast<const uint4*>(hb + (((unsigned)sB) << 9) + byteoff);
            fma8(acc, hA, aA);
            fma8(acc, hB, aB);
        }
        for (; j < m2; j += 2) {
            int jA = j + half;
            int sA = sp[jA];
            float aA = ap[jA * NHEAD];
            uint4 hA = *reinterpret_cast<const uint4*>(hb + (((unsigned)sA) << 9) + byteoff);
            fma8(acc, hA, aA);
        }
        if (dg > 64) {                    // rare slow path
            for (int i = t0 + 64; i < t1; ++i) {
                if (half == 0) {
                    int e = eidx[i];
                    int s = (e < E) ? ei[e] : (e - E);
                    float a = alpha[(size_t)e * NHEAD + head];
                    uint4 hv = *reinterpret_cast<const uint4*>(hb + (((unsigned)s) << 9) + byteoff);
                    fma8(acc, hv, a);
                }
            }
        }
#pragma unroll
        for (int k = 0; k < 8; ++k) acc[k] += __shfl_xor(acc[k], 32, 64);

        if (half == 0) {
            float4 b0 = *reinterpret_cast<const float4*>(&bias[q * 8]);
            float4 b1 = *reinterpret_cast<const float4*>(&bias[q * 8 + 4]);
            float v0 = acc[0] + b0.x, v1 = acc[1] + b0.y, v2 = acc[2] + b0.z, v3 = acc[3] + b0.w;
            float v4 = acc[4] + b1.x, v5 = acc[5] + b1.y, v6 = acc[6] + b1.z, v7 = acc[7] + b1.w;
            v0 = v0 > 0.f ? v0 : expm1f(v0);
            v1 = v1 > 0.f ? v1 : expm1f(v1);
            v2 = v2 > 0.f ? v2 : expm1f(v2);
            v3 = v3 > 0.f ? v3 : expm1f(v3);
            v4 = v4 > 0.f ? v4 : expm1f(v4);
            v5 = v5 > 0.f ? v5 : expm1f(v5);
            v6 = v6 > 0.f ? v6 : expm1f(v6);
            v7 = v7 > 0.f ? v7 : expm1f(v7);
            uint4 o;
            o.x = (unsigned)f2bf(v0) | ((unsigned)f2bf(v1) << 16);
            o.y = (unsigned)f2bf(v2) | ((unsigned)f2bf(v3) << 16);
            o.z = (unsigned)f2bf(v4) | ((unsigned)f2bf(v5) << 16);
            o.w = (unsigned)f2bf(v6) | ((unsigned)f2bf(v7) << 16);
            *reinterpret_cast<uint4*>(&xs[nl][q * 8]) = o;
        }
    }
}

// ================================================================ fused attn(L) + gemm(L+1), 32-node tile
// 512 threads = 8 waves. After phase A/B, xs holds 32 x-rows (bf16); GEMM phase:
// wave w -> row group (w&1), col group / head (w>>1). B traffic: 128KB per 32 rows.
__launch_bounds__(512, 4)
__global__ void attn_gemm_kernel(const unsigned short* __restrict__ h_in,
                                 const float* __restrict__ esrc_in,
                                 const float* __restrict__ edst_in,
                                 const int* __restrict__ ei,
                                 const int* __restrict__ rowptr,
                                 const int* __restrict__ eidx,
                                 const float* __restrict__ bias,          // b_L
                                 float* __restrict__ alpha,               // a_L out
                                 const unsigned short* __restrict__ Wt,   // W_{L+1}^T [col][K]
                                 unsigned short* __restrict__ Hout,       // h_{L+1}
                                 const float* __restrict__ As, const float* __restrict__ Ad,
                                 float* __restrict__ esrc_out, float* __restrict__ edst_out,
                                 int n, int E) {
    constexpr int K = 256;
    constexpr int LDX = K + 16;
    __shared__ __align__(16) float aT[32][64][NHEAD];
    __shared__ int sArr[32][64];
    __shared__ __align__(16) unsigned short xs[32][LDX];

    int nodeblk = blockIdx.x * 32;
    attn_phaseAB<LDX>(h_in, esrc_in, edst_in, ei, rowptr, eidx, bias, alpha,
                      aT, sArr, xs, nodeblk, n, E);
    __syncthreads();

    // ---------- gemm: h_next[32 rows] = xs @ W  + es/ed epilogue
    int tid = threadIdx.x;
    int lane = tid & 63;
    int w = tid >> 6;                              // 0..7
    int rg = w & 1;                                // row group (16 rows)
    int cg = w >> 1;                               // col group == head
    int lr = lane & 15;
    int lk = (lane >> 4) * 8;

    f32x4 acc[4];
#pragma unroll
    for (int nf = 0; nf < 4; ++nf) acc[nf] = (f32x4){0.f, 0.f, 0.f, 0.f};

    const unsigned short* wt = Wt + (size_t)(cg * 64) * K;
#pragma unroll
    for (int ks = 0; ks < K / 32; ++ks) {
        bf16x8 a = *reinterpret_cast<const bf16x8*>(&xs[16 * rg + lr][ks * 32 + lk]);
        bf16x8 b[4];
#pragma unroll
        for (int nf = 0; nf < 4; ++nf)
            b[nf] = *reinterpret_cast<const bf16x8*>(&wt[(size_t)(16 * nf + lr) * K + ks * 32 + lk]);
#pragma unroll
        for (int nf = 0; nf < 4; ++nf)
            acc[nf] = __builtin_amdgcn_mfma_f32_16x16x32_bf16(a, b[nf], acc[nf], 0, 0, 0);
    }

    float as_v[4], ad_v[4];
#pragma unroll
    for (int nf = 0; nf < 4; ++nf) {
        as_v[nf] = As[cg * 64 + 16 * nf + lr];
        ad_v[nf] = Ad[cg * 64 + 16 * nf + lr];
    }
#pragma unroll
    for (int j = 0; j < 4; ++j) {
        int row_g = nodeblk + 16 * rg + (lane >> 4) * 4 + j;
        bool ok = row_g < n;
#pragma unroll
        for (int nf = 0; nf < 4; ++nf) {
            if (ok) Hout[(size_t)row_g * HCOLS + cg * 64 + 16 * nf + lr] = f2bf(acc[nf][j]);
        }
        float ps = acc[0][j] * as_v[0] + acc[1][j] * as_v[1] +
                   acc[2][j] * as_v[2] + acc[3][j] * as_v[3];
        float pd = acc[0][j] * ad_v[0] + acc[1][j] * ad_v[1] +
                   acc[2][j] * ad_v[2] + acc[3][j] * ad_v[3];
#pragma unroll
        for (int off = 1; off < 16; off <<= 1) {
            ps += __shfl_xor(ps, off, 64);
            pd += __shfl_xor(pd, off, 64);
        }
        if (lr == 0 && ok) {
            esrc_out[row_g * NHEAD + cg] = ps;
            edst_out[row_g * NHEAD + cg] = pd;
        }
    }
}

// ---------------------------------------------------------------- final attn (head-mean), R5-proven
__launch_bounds__(256, 4)
__global__ void attn_mean_kernel(const unsigned short* __restrict__ h,
                                 const float* __restrict__ esrc,
                                 const float* __restrict__ edst,
                                 const int* __restrict__ ei,
                                 const int* __restrict__ rowptr,
                                 const int* __restrict__ eidx,
                                 const float* __restrict__ bias,
                                 float* __restrict__ alpha,
                                 float* __restrict__ xout,
                                 int n, int E) {
    __shared__ __align__(16) float aT[16][64][NHEAD];
    __shared__ int sArr[16][64];

    int tid = threadIdx.x;
    int wave = tid >> 6, lane = tid & 63;
    int g = lane >> 4, t = lane & 15;
    int nodeblk = blockIdx.x * 16;
    int nidx = wave * 4 + g;
    int node = nodeblk + nidx;
    bool gvalid = node < n;
    int s0 = 0, s1 = 0;
    if (gvalid) { s0 = rowptr[node]; s1 = rowptr[node + 1]; }
    int deg = s1 - s0;
    float4 ed = make_float4(0.f, 0.f, 0.f, 0.f);
    if (gvalid) ed = *reinterpret_cast<const float4*>(&edst[node * NHEAD]);

    const float NEGINF = -3.4e38f;
    float4 lgc[4]; int sc[4], ec[4];
    int degc = deg < 64 ? deg : 64;
    int nch = (degc + 15) >> 4;
    float4 mx = make_float4(NEGINF, NEGINF, NEGINF, NEGINF);
#pragma unroll
    for (int c = 0; c < 4; ++c) {
        sc[c] = 0; ec[c] = 0;
        lgc[c] = make_float4(NEGINF, NEGINF, NEGINF, NEGINF);
        if (c < nch) {
            int i = s0 + c * 16 + t;
            bool v = i < s1;
            int e = v ? eidx[i] : 0;
            int s = v ? ((e < E) ? ei[e] : (e - E)) : 0;
            sc[c] = s; ec[c] = e;
            if (v) {
                float4 es = *reinterpret_cast<const float4*>(&esrc[s * NHEAD]);
                lgc[c].x = leaky(es.x + ed.x);
                lgc[c].y = leaky(es.y + ed.y);
                lgc[c].z = leaky(es.z + ed.z);
                lgc[c].w = leaky(es.w + ed.w);
            }
            mx.x = fmaxf(mx.x, lgc[c].x);
            mx.y = fmaxf(mx.y, lgc[c].y);
            mx.z = fmaxf(mx.z, lgc[c].z);
            mx.w = fmaxf(mx.w, lgc[c].w);
        }
    }
    for (int i = s0 + 64 + t; i < s1; i += 16) {
        int e = eidx[i];
        int s = (e < E) ? ei[e] : (e - E);
        float4 es = *reinterpret_cast<const float4*>(&esrc[s * NHEAD]);
        mx.x = fmaxf(mx.x, leaky(es.x + ed.x));
        mx.y = fmaxf(mx.y, leaky(es.y + ed.y));
        mx.z = fmaxf(mx.z, leaky(es.z + ed.z));
        mx.w = fmaxf(mx.w, leaky(es.w + ed.w));
    }
#pragma unroll
    for (int off = 1; off < 16; off <<= 1) {
        mx.x = fmaxf(mx.x, __shfl_xor(mx.x, off, 64));
        mx.y = fmaxf(mx.y, __shfl_xor(mx.y, off, 64));
        mx.z = fmaxf(mx.z, __shfl_xor(mx.z, off, 64));
        mx.w = fmaxf(mx.w, __shfl_xor(mx.w, off, 64));
    }
    float4 exc[4];
    float4 sm = make_float4(0.f, 0.f, 0.f, 0.f);
#pragma unroll
    for (int c = 0; c < 4; ++c) {
        exc[c] = make_float4(0.f, 0.f, 0.f, 0.f);
        if (c < nch) {
            exc[c].x = __expf(lgc[c].x - mx.x);
            exc[c].y = __expf(lgc[c].y - mx.y);
            exc[c].z = __expf(lgc[c].z - mx.z);
            exc[c].w = __expf(lgc[c].w - mx.w);
            sm.x += exc[c].x; sm.y += exc[c].y; sm.z += exc[c].z; sm.w += exc[c].w;
        }
    }
    for (int i = s0 + 64 + t; i < s1; i += 16) {
        int e = eidx[i];
        int s = (e < E) ? ei[e] : (e - E);
        float4 es = *reinterpret_cast<const float4*>(&esrc[s * NHEAD]);
        sm.x += __expf(leaky(es.x + ed.x) - mx.x);
        sm.y += __expf(leaky(es.y + ed.y) - mx.y);
        sm.z += __expf(leaky(es.z + ed.z) - mx.z);
        sm.w += __expf(leaky(es.w + ed.w) - mx.w);
    }
#pragma unroll
    for (int off = 1; off < 16; off <<= 1) {
        sm.x += __shfl_xor(sm.x, off, 64);
        sm.y += __shfl_xor(sm.y, off, 64);
        sm.z += __shfl_xor(sm.z, off, 64);
        sm.w += __shfl_xor(sm.w, off, 64);
    }
    float4 inv = make_float4(1.f / sm.x, 1.f / sm.y, 1.f / sm.z, 1.f / sm.w);
#pragma unroll
    for (int c = 0; c < 4; ++c) {
        if (c < nch) {
            float4 al4;
            al4.x = exc[c].x * inv.x; al4.y = exc[c].y * inv.y;
            al4.z = exc[c].z * inv.z; al4.w = exc[c].w * inv.w;
            int i = s0 + c * 16 + t;
            if (i < s1) *reinterpret_cast<float4*>(&alpha[(size_t)ec[c] * NHEAD]) = al4;
            int eo = c * 16 + t;
            *reinterpret_cast<float4*>(&aT[nidx][eo][0]) = al4;
            sArr[nidx][eo] = sc[c];
        }
    }
    for (int i = s0 + 64 + t; i < s1; i += 16) {
        int e = eidx[i];
        int s = (e < E) ? ei[e] : (e - E);
        float4 es = *reinterpret_cast<const float4*>(&esrc[s * NHEAD]);
        float4 av;
        av.x = __expf(leaky(es.x + ed.x) - mx.x) * inv.x;
        av.y = __expf(leaky(es.y + ed.y) - mx.y) * inv.y;
        av.z = __expf(leaky(es.z + ed.z) - mx.z) * inv.z;
        av.w = __expf(leaky(es.w + ed.w) - mx.w) * inv.w;
        *reinterpret_cast<float4*>(&alpha[(size_t)e * NHEAD]) = av;
    }
    if (__any(deg > 64)) __threadfence();

    asm volatile("s_waitcnt lgkmcnt(0)" ::: "memory");
    __builtin_amdgcn_sched_barrier(0);

    int half = lane >> 5;
    int q = lane & 31;
    int head = q >> 3;
    unsigned byteoff = (unsigned)q * 16u;
    const char* hb = (const char*)h;

    for (int g2 = 0; g2 < 4; ++g2) {
        int nl = wave * 4 + g2;
        int nd = nodeblk + nl;
        if (nd >= n) continue;
        int t0 = rowptr[nd], t1 = rowptr[nd + 1];
        int dg = t1 - t0;
        int m = dg < 64 ? dg : 64;
        int m2 = (m + 1) & ~1;
        const float* ap = &aT[nl][0][0] + head;
        const int* sp = &sArr[nl][0];
        float acc[8];
#pragma unroll
        for (int k = 0; k < 8; ++k) acc[k] = 0.f;
        int j = 0;
        for (; j + 4 <= m2; j += 4) {
            int jA = j + half, jB = j + 2 + half;
            int sA = sp[jA], sB = sp[jB];
            float aA = ap[jA * NHEAD], aB = ap[jB * NHEAD];
            uint4 hA = *reinterpret_cast<const uint4*>(hb + (((unsigned)sA) << 9) + byteoff);
            uint4 hB = *reinterpret_cast<const uint4*>(hb + (((unsigned)sB) << 9) + byteoff);
            fma8(acc, hA, aA);
            fma8(acc, hB, aB);
        }
        for (; j < m2; j += 2) {
            int jA = j + half;
            int sA = sp[jA];
            float aA = ap[jA * NHEAD];
            uint4 hA = *reinterpret_cast<const uint4*>(hb + (((unsigned)sA) << 9) + byteoff);
            fma8(acc, hA, aA);
        }
        if (dg > 64) {
            for (int i = t0 + 64; i < t1; ++i) {
                if (half == 0) {
                    int e = eidx[i];
                    int s = (e < E) ? ei[e] : (e - E);
                    float a = alpha[(size_t)e * NHEAD + head];
                    uint4 hv = *reinterpret_cast<const uint4*>(hb + (((unsigned)s) << 9) + byteoff);
                    fma8(acc, hv, a);
                }
            }
        }
#pragma unroll
        for (int k = 0; k < 8; ++k) {
            acc[k] += __shfl_xor(acc[k], 32, 64);
            acc[k] += __shfl_xor(acc[k], 8, 64);
            acc[k] += __shfl_xor(acc[k], 16, 64);
        }
        if (half == 0 && q < 8) {
            float* op = xout + (size_t)nd * CDIM + q * 8;
            float4 r0, r1;
            r0.x = acc[0] * 0.25f + bias[q * 8 + 0];
            r0.y = acc[1] * 0.25f + bias[q * 8 + 1];
            r0.z = acc[2] * 0.25f + bias[q * 8 + 2];
            r0.w = acc[3] * 0.25f + bias[q * 8 + 3];
            r1.x = acc[4] * 0.25f + bias[q * 8 + 4];
            r1.y = acc[5] * 0.25f + bias[q * 8 + 5];
            r1.z = acc[6] * 0.25f + bias[q * 8 + 6];
            r1.w = acc[7] * 0.25f + bias[q * 8 + 7];
            *reinterpret_cast<float4*>(op)     = r0;
            *reinterpret_cast<float4*>(op + 4) = r1;
        }
    }
}

// ---------------------------------------------------------------- launch
extern "C" void kernel_launch(void* const* d_in, const int* in_sizes, int n_in,
                              void* d_out, int out_size, void* d_ws, size_t ws_size,
                              hipStream_t stream) {
    const float* x   = (const float*)d_in[0];
    const int*   ei  = (const int*)d_in[1];
    const float* W0  = (const float*)d_in[2];
    const float* as0 = (const float*)d_in[3];
    const float* ad0 = (const float*)d_in[4];
    const float* b0  = (const float*)d_in[5];
    const float* W1  = (const float*)d_in[6];
    const float* as1 = (const float*)d_in[7];
    const float* ad1 = (const float*)d_in[8];
    const float* b1  = (const float*)d_in[9];
    const float* W2  = (const float*)d_in[10];
    const float* as2 = (const float*)d_in[11];
    const float* ad2 = (const float*)d_in[12];
    const float* b2  = (const float*)d_in[13];

    const int N  = in_sizes[0] / 128;
    const int E  = in_sizes[1] / 2;
    const int Ep = E + N;

    float* out = (float*)d_out;
    float* a0  = out + (size_t)N * CDIM;
    float* a1  = a0 + (size_t)Ep * NHEAD;
    float* a2  = a1 + (size_t)Ep * NHEAD;

    char* wp = (char*)d_ws;
    auto carve = [&](size_t bytes) {
        char* p = wp;
        wp += (bytes + 255) & ~(size_t)255;
        return (void*)p;
    };
    unsigned short* hbufA = (unsigned short*)carve((size_t)N * HCOLS * 2);   // bf16
    unsigned short* hbufB = (unsigned short*)carve((size_t)N * HCOLS * 2);   // bf16
    float* esrcA  = (float*)carve((size_t)N * NHEAD * 4);
    float* edstA  = (float*)carve((size_t)N * NHEAD * 4);
    float* esrcB  = (float*)carve((size_t)N * NHEAD * 4);
    float* edstB  = (float*)carve((size_t)N * NHEAD * 4);
    int*   deg    = (int*)carve((size_t)N * 4);
    int*   rowptr = (int*)carve((size_t)(N + 1) * 4);
    int*   cursor = (int*)carve((size_t)N * 4);
    int*   eidx   = (int*)carve((size_t)Ep * 4);
    unsigned short* Wt0 = (unsigned short*)carve((size_t)HCOLS * 128 * 2);
    unsigned short* Wt1 = (unsigned short*)carve((size_t)HCOLS * HCOLS * 2);
    unsigned short* Wt2 = (unsigned short*)carve((size_t)HCOLS * HCOLS * 2);

    // prep: zero deg + W->bf16 transposed (single launch)
    int nzb = (N + 255) / 256;
    prep_kernel<<<nzb + 192, 256, 0, stream>>>(W0, W1, W2, Wt0, Wt1, Wt2, deg, N, nzb);
    deg_kernel<<<(Ep + 255) / 256, 256, 0, stream>>>(ei, deg, E, Ep);
    scan_kernel<<<1, 1024, 0, stream>>>(deg, rowptr, cursor, N);
    fill_kernel<<<(Ep + 255) / 256, 256, 0, stream>>>(ei, cursor, eidx, E, Ep);

    int gemm_grid  = (N + 31) / 32;
    int fused_grid = (N + 31) / 32;
    int mean_grid  = (N + 15) / 16;

    // ---- layer 0 GEMM (K = 128, fp32 source) -> h0 (A), es0/ed0 (A)
    gemm_kernel<128, true><<<gemm_grid, 256, 0, stream>>>(x, Wt0, hbufA, as0, ad0, esrcA, edstA, N);
    // ---- attn0 + gemm1 fused -> a0, h1 (B), es1/ed1 (B)
    attn_gemm_kernel<<<fused_grid, 512, 0, stream>>>(hbufA, esrcA, edstA, ei, rowptr, eidx,
                                                     b0, a0, Wt1, hbufB, as1, ad1, esrcB, edstB, N, E);
    // ---- attn1 + gemm2 fused -> a1, h2 (A), es2/ed2 (A)
    attn_gemm_kernel<<<fused_grid, 512, 0, stream>>>(hbufB, esrcB, edstB, ei, rowptr, eidx,
                                                     b1, a1, Wt2, hbufA, as2, ad2, esrcA, edstA, N, E);
    // ---- attn2 (head-mean) -> a2, out
    attn_mean_kernel<<<mean_grid, 256, 0, stream>>>(hbufA, esrcA, edstA, ei, rowptr, eidx,
                                                    b2, a2, out, N, E);
}

// Round 10
// 218.509 us; speedup vs baseline: 1.1369x; 1.1369x over previous
//
#include <hip/hip_runtime.h>
#include <hip/hip_bf16.h>
#include <math.h>

#define HCOLS 256          // H * C = 4 * 64, hidden width for all layers
#define NHEAD 4
#define CDIM  64
#define NEG_SLOPE 0.2f

typedef __attribute__((ext_vector_type(8))) short bf16x8;
typedef __attribute__((ext_vector_type(4))) float f32x4;

__device__ __forceinline__ float leaky(float v) { return v > 0.f ? v : v * NEG_SLOPE; }
__device__ __forceinline__ unsigned short f2bf(float f) {      // RNE
    unsigned u = __float_as_uint(f);
    u += 0x7fff + ((u >> 16) & 1);
    return (unsigned short)(u >> 16);
}

// expand uint4 (8 bf16) and fma into acc[8] with scalar a
__device__ __forceinline__ void fma8(float* acc, uint4 hv, float a) {
    acc[0] = fmaf(a, __uint_as_float(hv.x << 16),          acc[0]);
    acc[1] = fmaf(a, __uint_as_float(hv.x & 0xffff0000u),  acc[1]);
    acc[2] = fmaf(a, __uint_as_float(hv.y << 16),          acc[2]);
    acc[3] = fmaf(a, __uint_as_float(hv.y & 0xffff0000u),  acc[3]);
    acc[4] = fmaf(a, __uint_as_float(hv.z << 16),          acc[4]);
    acc[5] = fmaf(a, __uint_as_float(hv.z & 0xffff0000u),  acc[5]);
    acc[6] = fmaf(a, __uint_as_float(hv.w << 16),          acc[6]);
    acc[7] = fmaf(a, __uint_as_float(hv.w & 0xffff0000u),  acc[7]);
}

// ---------------------------------------------------------------- prep: zero deg + W transpose/convert
__global__ void prep_kernel(const float* __restrict__ W0, const float* __restrict__ W1,
                            const float* __restrict__ W2,
                            unsigned short* __restrict__ Wt0, unsigned short* __restrict__ Wt1,
                            unsigned short* __restrict__ Wt2,
                            int* __restrict__ deg, int n, int nzb) {
    int b = blockIdx.x;
    if (b < nzb) {
        int i = b * 256 + threadIdx.x;
        if (i < n) deg[i] = 0;
        return;
    }
    b -= nzb;
    int z = b >> 6;                      // 64 tiles per matrix
    int rem = b & 63;
    int bx = rem & 7, by = rem >> 3;
    const float* W = (z == 0) ? W0 : (z == 1) ? W1 : W2;
    unsigned short* Wt = (z == 0) ? Wt0 : (z == 1) ? Wt1 : Wt2;
    int K = (z == 0) ? 128 : 256;
    if (by * 32 >= K) return;
    __shared__ float t[32][33];
    int tx = threadIdx.x & 31, ty = threadIdx.x >> 5;   // 32 x 8
#pragma unroll
    for (int i = 0; i < 32; i += 8)
        t[ty + i][tx] = W[(by * 32 + ty + i) * HCOLS + bx * 32 + tx];
    __syncthreads();
#pragma unroll
    for (int i = 0; i < 32; i += 8)
        Wt[(size_t)(bx * 32 + ty + i) * K + by * 32 + tx] = f2bf(t[tx][ty + i]);
}

// ---------------------------------------------------------------- CSR build
__global__ void deg_kernel(const int* __restrict__ ei, int* __restrict__ deg,
                           int E, int Ep) {
    int e = blockIdx.x * 256 + threadIdx.x;
    if (e >= Ep) return;
    int d = (e < E) ? ei[E + e] : (e - E);
    atomicAdd(&deg[d], 1);
}

__global__ void scan_kernel(const int* __restrict__ deg, int* __restrict__ rowptr,
                            int* __restrict__ cursor, int n) {
    __shared__ int wsum[16];
    int tid = threadIdx.x;
    int lane = tid & 63, w = tid >> 6;
    int CH = (n + 1023) >> 10;
    int base = tid * CH;
    int s = 0;
    for (int k = 0; k < CH; ++k) {
        int i = base + k;
        s += (i < n) ? deg[i] : 0;
    }
    int incl = s;
#pragma unroll
    for (int d = 1; d < 64; d <<= 1) {
        int t = __shfl_up(incl, d, 64);
        if (lane >= d) incl += t;
    }
    if (lane == 63) wsum[w] = incl;
    __syncthreads();
    if (w == 0) {
        int v = (lane < 16) ? wsum[lane] : 0;
#pragma unroll
        for (int d = 1; d < 16; d <<= 1) {
            int t = __shfl_up(v, d, 64);
            if (lane >= d) v += t;
        }
        if (lane < 16) wsum[lane] = v;
    }
    __syncthreads();
    int woff = (w == 0) ? 0 : wsum[w - 1];
    int run = woff + incl - s;
    for (int k = 0; k < CH; ++k) {
        int i = base + k;
        if (i < n) { rowptr[i] = run; cursor[i] = run; run += deg[i]; }
    }
    if (tid == 1023) rowptr[n] = run;
}

__global__ void fill_kernel(const int* __restrict__ ei, int* __restrict__ cursor,
                            int* __restrict__ eidx, int E, int Ep) {
    int e = blockIdx.x * 256 + threadIdx.x;
    if (e >= Ep) return;
    int d = (e < E) ? ei[E + e] : (e - E);
    int pos = atomicAdd(&cursor[d], 1);
    eidx[pos] = e;
}

// ---------------------------------------------------------------- standalone MFMA GEMM (layer 0)
template <int K, bool SRC_F32>
__global__ void gemm_kernel(const void* __restrict__ Xv, const unsigned short* __restrict__ Wt,
                            unsigned short* __restrict__ Hout,
                            const float* __restrict__ As, const float* __restrict__ Ad,
                            float* __restrict__ esrc, float* __restrict__ edst,
                            int n) {
    constexpr int LDK = K + 16;
    __shared__ __align__(16) unsigned short a_sh[32 * LDK];
    int row0 = blockIdx.x * 32;
    int tid = threadIdx.x;

    constexpr int CH = 32 * K / 8;                  // 16B chunks
    for (int c = tid; c < CH; c += 256) {
        int r = c / (K / 8), kc = c % (K / 8);
        int row = row0 + r;
        uint4 pack;
        if (row < n) {
            if (SRC_F32) {
                const float* X = (const float*)Xv;
                float4 f0 = *reinterpret_cast<const float4*>(&X[(size_t)row * K + kc * 8]);
                float4 f1 = *reinterpret_cast<const float4*>(&X[(size_t)row * K + kc * 8 + 4]);
                pack.x = f2bf(f0.x) | ((unsigned)f2bf(f0.y) << 16);
                pack.y = f2bf(f0.z) | ((unsigned)f2bf(f0.w) << 16);
                pack.z = f2bf(f1.x) | ((unsigned)f2bf(f1.y) << 16);
                pack.w = f2bf(f1.z) | ((unsigned)f2bf(f1.w) << 16);
            } else {
                const uint4* X = (const uint4*)Xv;
                pack = X[((size_t)row * K + kc * 8) / 8];
            }
        } else {
            pack = make_uint4(0, 0, 0, 0);
        }
        *reinterpret_cast<uint4*>(&a_sh[r * LDK + kc * 8]) = pack;
    }
    __syncthreads();

    int lane = tid & 63;
    int w = tid >> 6;                              // wave == head
    int lr = lane & 15;
    int lk = (lane >> 4) * 8;

    f32x4 acc[2][4];
#pragma unroll
    for (int m = 0; m < 2; ++m)
#pragma unroll
        for (int nf = 0; nf < 4; ++nf) acc[m][nf] = (f32x4){0.f, 0.f, 0.f, 0.f};

    const unsigned short* wt = Wt + (size_t)(w * 64) * K;
#pragma unroll
    for (int ks = 0; ks < K / 32; ++ks) {
        bf16x8 a[2], b[4];
#pragma unroll
        for (int m = 0; m < 2; ++m)
            a[m] = *reinterpret_cast<const bf16x8*>(&a_sh[(16 * m + lr) * LDK + ks * 32 + lk]);
#pragma unroll
        for (int nf = 0; nf < 4; ++nf)
            b[nf] = *reinterpret_cast<const bf16x8*>(&wt[(size_t)(16 * nf + lr) * K + ks * 32 + lk]);
#pragma unroll
        for (int m = 0; m < 2; ++m)
#pragma unroll
            for (int nf = 0; nf < 4; ++nf)
                acc[m][nf] = __builtin_amdgcn_mfma_f32_16x16x32_bf16(a[m], b[nf], acc[m][nf], 0, 0, 0);
    }

    float as_v[4], ad_v[4];
#pragma unroll
    for (int nf = 0; nf < 4; ++nf) {
        as_v[nf] = As[w * 64 + 16 * nf + lr];
        ad_v[nf] = Ad[w * 64 + 16 * nf + lr];
    }
#pragma unroll
    for (int m = 0; m < 2; ++m) {
#pragma unroll
        for (int j = 0; j < 4; ++j) {
            int row_g = row0 + 16 * m + (lane >> 4) * 4 + j;
            bool ok = row_g < n;
#pragma unroll
            for (int nf = 0; nf < 4; ++nf) {
                if (ok) Hout[(size_t)row_g * HCOLS + w * 64 + 16 * nf + lr] = f2bf(acc[m][nf][j]);
            }
            float ps = acc[m][0][j] * as_v[0] + acc[m][1][j] * as_v[1] +
                       acc[m][2][j] * as_v[2] + acc[m][3][j] * as_v[3];
            float pd = acc[m][0][j] * ad_v[0] + acc[m][1][j] * ad_v[1] +
                       acc[m][2][j] * ad_v[2] + acc[m][3][j] * ad_v[3];
#pragma unroll
            for (int off = 1; off < 16; off <<= 1) {
                ps += __shfl_xor(ps, off, 64);
                pd += __shfl_xor(pd, off, 64);
            }
            if (lr == 0 && ok) {
                esrc[row_g * NHEAD + w] = ps;
                edst[row_g * NHEAD + w] = pd;
            }
        }
    }
}

// ================================================================ shared phase A+B body (R8 base, 8-edge MLP)
template <int LDX>
__device__ __forceinline__ void attn_phaseAB(
        const unsigned short* __restrict__ h,
        const float* __restrict__ esrc, const float* __restrict__ edst,
        const int* __restrict__ ei, const int* __restrict__ rowptr,
        const int* __restrict__ eidx, const float* __restrict__ bias,
        float* __restrict__ alpha,
        float (*aT)[64][NHEAD], int (*sArr)[64], unsigned short (*xs)[LDX],
        int nodeblk, int n, int E) {
    int tid = threadIdx.x;
    int wave = tid >> 6, lane = tid & 63;
    int g = lane >> 4, t = lane & 15;
    int nidx = wave * 4 + g;
    int node = nodeblk + nidx;
    bool gvalid = node < n;
    int s0 = 0, s1 = 0;
    if (gvalid) { s0 = rowptr[node]; s1 = rowptr[node + 1]; }
    int deg = s1 - s0;
    float4 ed = make_float4(0.f, 0.f, 0.f, 0.f);
    if (gvalid) ed = *reinterpret_cast<const float4*>(&edst[node * NHEAD]);

    // ---------- phase A: segment softmax (16-lane group per node)
    const float NEGINF = -3.4e38f;
    float4 lgc[4]; int sc[4], ec[4];
    int degc = deg < 64 ? deg : 64;
    int nch = (degc + 15) >> 4;
    float4 mx = make_float4(NEGINF, NEGINF, NEGINF, NEGINF);
#pragma unroll
    for (int c = 0; c < 4; ++c) {
        sc[c] = 0; ec[c] = 0;
        lgc[c] = make_float4(NEGINF, NEGINF, NEGINF, NEGINF);
        if (c < nch) {
            int i = s0 + c * 16 + t;
            bool v = i < s1;
            int e = v ? eidx[i] : 0;
            int s = v ? ((e < E) ? ei[e] : (e - E)) : 0;
            sc[c] = s; ec[c] = e;
            if (v) {
                float4 es = *reinterpret_cast<const float4*>(&esrc[s * NHEAD]);
                lgc[c].x = leaky(es.x + ed.x);
                lgc[c].y = leaky(es.y + ed.y);
                lgc[c].z = leaky(es.z + ed.z);
                lgc[c].w = leaky(es.w + ed.w);
            }
            mx.x = fmaxf(mx.x, lgc[c].x);
            mx.y = fmaxf(mx.y, lgc[c].y);
            mx.z = fmaxf(mx.z, lgc[c].z);
            mx.w = fmaxf(mx.w, lgc[c].w);
        }
    }
    for (int i = s0 + 64 + t; i < s1; i += 16) {   // rare: deg > 64
        int e = eidx[i];
        int s = (e < E) ? ei[e] : (e - E);
        float4 es = *reinterpret_cast<const float4*>(&esrc[s * NHEAD]);
        mx.x = fmaxf(mx.x, leaky(es.x + ed.x));
        mx.y = fmaxf(mx.y, leaky(es.y + ed.y));
        mx.z = fmaxf(mx.z, leaky(es.z + ed.z));
        mx.w = fmaxf(mx.w, leaky(es.w + ed.w));
    }
#pragma unroll
    for (int off = 1; off < 16; off <<= 1) {
        mx.x = fmaxf(mx.x, __shfl_xor(mx.x, off, 64));
        mx.y = fmaxf(mx.y, __shfl_xor(mx.y, off, 64));
        mx.z = fmaxf(mx.z, __shfl_xor(mx.z, off, 64));
        mx.w = fmaxf(mx.w, __shfl_xor(mx.w, off, 64));
    }
    float4 exc[4];
    float4 sm = make_float4(0.f, 0.f, 0.f, 0.f);
#pragma unroll
    for (int c = 0; c < 4; ++c) {
        exc[c] = make_float4(0.f, 0.f, 0.f, 0.f);
        if (c < nch) {
            exc[c].x = __expf(lgc[c].x - mx.x);   // invalid lanes: exp(-inf)=0
            exc[c].y = __expf(lgc[c].y - mx.y);
            exc[c].z = __expf(lgc[c].z - mx.z);
            exc[c].w = __expf(lgc[c].w - mx.w);
            sm.x += exc[c].x; sm.y += exc[c].y; sm.z += exc[c].z; sm.w += exc[c].w;
        }
    }
    for (int i = s0 + 64 + t; i < s1; i += 16) {   // rare
        int e = eidx[i];
        int s = (e < E) ? ei[e] : (e - E);
        float4 es = *reinterpret_cast<const float4*>(&esrc[s * NHEAD]);
        sm.x += __expf(leaky(es.x + ed.x) - mx.x);
        sm.y += __expf(leaky(es.y + ed.y) - mx.y);
        sm.z += __expf(leaky(es.z + ed.z) - mx.z);
        sm.w += __expf(leaky(es.w + ed.w) - mx.w);
    }
#pragma unroll
    for (int off = 1; off < 16; off <<= 1) {
        sm.x += __shfl_xor(sm.x, off, 64);
        sm.y += __shfl_xor(sm.y, off, 64);
        sm.z += __shfl_xor(sm.z, off, 64);
        sm.w += __shfl_xor(sm.w, off, 64);
    }
    float4 inv = make_float4(1.f / sm.x, 1.f / sm.y, 1.f / sm.z, 1.f / sm.w);
#pragma unroll
    for (int c = 0; c < 4; ++c) {
        if (c < nch) {
            float4 al4;
            al4.x = exc[c].x * inv.x; al4.y = exc[c].y * inv.y;
            al4.z = exc[c].z * inv.z; al4.w = exc[c].w * inv.w;
            int i = s0 + c * 16 + t;
            if (i < s1) *reinterpret_cast<float4*>(&alpha[(size_t)ec[c] * NHEAD]) = al4;
            *reinterpret_cast<float4*>(&aT[nidx][c * 16 + t][0]) = al4;  // 0 for invalid lanes
            sArr[nidx][c * 16 + t] = sc[c];
        }
    }
    for (int i = s0 + 64 + t; i < s1; i += 16) {   // rare
        int e = eidx[i];
        int s = (e < E) ? ei[e] : (e - E);
        float4 es = *reinterpret_cast<const float4*>(&esrc[s * NHEAD]);
        float4 av;
        av.x = __expf(leaky(es.x + ed.x) - mx.x) * inv.x;
        av.y = __expf(leaky(es.y + ed.y) - mx.y) * inv.y;
        av.z = __expf(leaky(es.z + ed.z) - mx.z) * inv.z;
        av.w = __expf(leaky(es.w + ed.w) - mx.w) * inv.w;
        *reinterpret_cast<float4*>(&alpha[(size_t)e * NHEAD]) = av;
    }
    if (__any(deg > 64)) __threadfence();

    asm volatile("s_waitcnt lgkmcnt(0)" ::: "memory");   // same-wave LDS write->read
    __builtin_amdgcn_sched_barrier(0);

    // ---------- phase B: x[node] = ELU(bias + sum_e alpha[e] * h[src(e)]) -> xs (bf16)
    // 8 edges per iteration (4 independent dwordx4 loads in flight per wave).
    // Padding safe: aT/sArr zero-filled up to nch*16 >= (deg+7)&~7; alpha=0 rows add 0.
    int half = lane >> 5;                 // which edge of the pair
    int q = lane & 31;                    // 16B slot within 512B row
    int head = q >> 3;
    unsigned byteoff = (unsigned)q * 16u;
    const char* hb = (const char*)h;

    for (int g2 = 0; g2 < 4; ++g2) {
        int nl = wave * 4 + g2;
        int nd = nodeblk + nl;
        if (nd >= n) continue;
        int t0 = rowptr[nd], t1 = rowptr[nd + 1];
        int dg = t1 - t0;
        int m = dg < 64 ? dg : 64;
        int m8 = (m + 7) & ~7;
        const float* ap = &aT[nl][0][0] + head;
        const int* sp = &sArr[nl][0];
        float acc[8];
#pragma unroll
        for (int k = 0; k < 8; ++k) acc[k] = 0.f;
        for (int j = 0; j < m8; j += 8) {
            int jA = j + half, jB = j + 2 + half, jC = j + 4 + half, jD = j + 6 + half;
            int sA = sp[jA], sB = sp[jB], sC = sp[jC], sD = sp[jD];
            float aA = ap[jA * NHEAD], aB = ap[jB * NHEAD];
            float aC = ap[jC * NHEAD], aD = ap[jD * NHEAD];
            uint4 hA = *reinterpret_cast<const uint4*>(hb + (((unsigned)sA) << 9) + byteoff);
            uint4 hB = *reinterpret_cast<const uint4*>(hb + (((unsigned)sB) << 9) + byteoff);
            uint4 hC = *reinterpret_cast<const uint4*>(hb + (((unsigned)sC) << 9) + byteoff);
            uint4 hD = *reinterpret_cast<const uint4*>(hb + (((unsigned)sD) << 9) + byteoff);
            fma8(acc, hA, aA);
            fma8(acc, hB, aB);
            fma8(acc, hC, aC);
            fma8(acc, hD, aD);
        }
        if (dg > 64) {                    // rare slow path
            for (int i = t0 + 64; i < t1; ++i) {
                if (half == 0) {
                    int e = eidx[i];
                    int s = (e < E) ? ei[e] : (e - E);
                    float a = alpha[(size_t)e * NHEAD + head];
                    uint4 hv = *reinterpret_cast<const uint4*>(hb + (((unsigned)s) << 9) + byteoff);
                    fma8(acc, hv, a);
                }
            }
        }
#pragma unroll
        for (int k = 0; k < 8; ++k) acc[k] += __shfl_xor(acc[k], 32, 64);

        if (half == 0) {
            float4 b0 = *reinterpret_cast<const float4*>(&bias[q * 8]);
            float4 b1 = *reinterpret_cast<const float4*>(&bias[q * 8 + 4]);
            float v0 = acc[0] + b0.x, v1 = acc[1] + b0.y, v2 = acc[2] + b0.z, v3 = acc[3] + b0.w;
            float v4 = acc[4] + b1.x, v5 = acc[5] + b1.y, v6 = acc[6] + b1.z, v7 = acc[7] + b1.w;
            v0 = v0 > 0.f ? v0 : expm1f(v0);
            v1 = v1 > 0.f ? v1 : expm1f(v1);
            v2 = v2 > 0.f ? v2 : expm1f(v2);
            v3 = v3 > 0.f ? v3 : expm1f(v3);
            v4 = v4 > 0.f ? v4 : expm1f(v4);
            v5 = v5 > 0.f ? v5 : expm1f(v5);
            v6 = v6 > 0.f ? v6 : expm1f(v6);
            v7 = v7 > 0.f ? v7 : expm1f(v7);
            uint4 o;
            o.x = (unsigned)f2bf(v0) | ((unsigned)f2bf(v1) << 16);
            o.y = (unsigned)f2bf(v2) | ((unsigned)f2bf(v3) << 16);
            o.z = (unsigned)f2bf(v4) | ((unsigned)f2bf(v5) << 16);
            o.w = (unsigned)f2bf(v6) | ((unsigned)f2bf(v7) << 16);
            *reinterpret_cast<uint4*>(&xs[nl][q * 8]) = o;
        }
    }
}

// ================================================================ fused attn(L) + gemm(L+1), 16-node tile (R8)
__launch_bounds__(256, 4)
__global__ void attn_gemm_kernel(const unsigned short* __restrict__ h_in,
                                 const float* __restrict__ esrc_in,
                                 const float* __restrict__ edst_in,
                                 const int* __restrict__ ei,
                                 const int* __restrict__ rowptr,
                                 const int* __restrict__ eidx,
                                 const float* __restrict__ bias,          // b_L
                                 float* __restrict__ alpha,               // a_L out
                                 const unsigned short* __restrict__ Wt,   // W_{L+1}^T [col][K]
                                 unsigned short* __restrict__ Hout,       // h_{L+1}
                                 const float* __restrict__ As, const float* __restrict__ Ad,
                                 float* __restrict__ esrc_out, float* __restrict__ edst_out,
                                 int n, int E) {
    constexpr int K = 256;
    constexpr int LDX = K + 16;
    __shared__ __align__(16) float aT[16][64][NHEAD];
    __shared__ int sArr[16][64];
    __shared__ __align__(16) unsigned short xs[16][LDX];

    int nodeblk = blockIdx.x * 16;
    attn_phaseAB<LDX>(h_in, esrc_in, edst_in, ei, rowptr, eidx, bias, alpha,
                      aT, sArr, xs, nodeblk, n, E);
    __syncthreads();

    // ---------- gemm: h_next[16 rows] = xs @ W  + es/ed epilogue
    int tid = threadIdx.x;
    int lane = tid & 63;
    int w = tid >> 6;                              // wave == head-col-group
    int lr = lane & 15;
    int lk = (lane >> 4) * 8;

    f32x4 acc[4];
#pragma unroll
    for (int nf = 0; nf < 4; ++nf) acc[nf] = (f32x4){0.f, 0.f, 0.f, 0.f};

    const unsigned short* wt = Wt + (size_t)(w * 64) * K;
#pragma unroll
    for (int ks = 0; ks < K / 32; ++ks) {
        bf16x8 a = *reinterpret_cast<const bf16x8*>(&xs[lr][ks * 32 + lk]);
        bf16x8 b[4];
#pragma unroll
        for (int nf = 0; nf < 4; ++nf)
            b[nf] = *reinterpret_cast<const bf16x8*>(&wt[(size_t)(16 * nf + lr) * K + ks * 32 + lk]);
#pragma unroll
        for (int nf = 0; nf < 4; ++nf)
            acc[nf] = __builtin_amdgcn_mfma_f32_16x16x32_bf16(a, b[nf], acc[nf], 0, 0, 0);
    }

    float as_v[4], ad_v[4];
#pragma unroll
    for (int nf = 0; nf < 4; ++nf) {
        as_v[nf] = As[w * 64 + 16 * nf + lr];
        ad_v[nf] = Ad[w * 64 + 16 * nf + lr];
    }
#pragma unroll
    for (int j = 0; j < 4; ++j) {
        int row_g = nodeblk + (lane >> 4) * 4 + j;
        bool ok = row_g < n;
#pragma unroll
        for (int nf = 0; nf < 4; ++nf) {
            if (ok) Hout[(size_t)row_g * HCOLS + w * 64 + 16 * nf + lr] = f2bf(acc[nf][j]);
        }
        float ps = acc[0][j] * as_v[0] + acc[1][j] * as_v[1] +
                   acc[2][j] * as_v[2] + acc[3][j] * as_v[3];
        float pd = acc[0][j] * ad_v[0] + acc[1][j] * ad_v[1] +
                   acc[2][j] * ad_v[2] + acc[3][j] * ad_v[3];
#pragma unroll
        for (int off = 1; off < 16; off <<= 1) {
            ps += __shfl_xor(ps, off, 64);
            pd += __shfl_xor(pd, off, 64);
        }
        if (lr == 0 && ok) {
            esrc_out[row_g * NHEAD + w] = ps;
            edst_out[row_g * NHEAD + w] = pd;
        }
    }
}

// ---------------------------------------------------------------- final attn (head-mean), 8-edge MLP
__launch_bounds__(256, 4)
__global__ void attn_mean_kernel(const unsigned short* __restrict__ h,
                                 const float* __restrict__ esrc,
                                 const float* __restrict__ edst,
                                 const int* __restrict__ ei,
                                 const int* __restrict__ rowptr,
                                 const int* __restrict__ eidx,
                                 const float* __restrict__ bias,
                                 float* __restrict__ alpha,
                                 float* __restrict__ xout,
                                 int n, int E) {
    __shared__ __align__(16) float aT[16][64][NHEAD];
    __shared__ int sArr[16][64];

    int tid = threadIdx.x;
    int wave = tid >> 6, lane = tid & 63;
    int g = lane >> 4, t = lane & 15;
    int nodeblk = blockIdx.x * 16;
    int nidx = wave * 4 + g;
    int node = nodeblk + nidx;
    bool gvalid = node < n;
    int s0 = 0, s1 = 0;
    if (gvalid) { s0 = rowptr[node]; s1 = rowptr[node + 1]; }
    int deg = s1 - s0;
    float4 ed = make_float4(0.f, 0.f, 0.f, 0.f);
    if (gvalid) ed = *reinterpret_cast<const float4*>(&edst[node * NHEAD]);

    const float NEGINF = -3.4e38f;
    float4 lgc[4]; int sc[4], ec[4];
    int degc = deg < 64 ? deg : 64;
    int nch = (degc + 15) >> 4;
    float4 mx = make_float4(NEGINF, NEGINF, NEGINF, NEGINF);
#pragma unroll
    for (int c = 0; c < 4; ++c) {
        sc[c] = 0; ec[c] = 0;
        lgc[c] = make_float4(NEGINF, NEGINF, NEGINF, NEGINF);
        if (c < nch) {
            int i = s0 + c * 16 + t;
            bool v = i < s1;
            int e = v ? eidx[i] : 0;
            int s = v ? ((e < E) ? ei[e] : (e - E)) : 0;
            sc[c] = s; ec[c] = e;
            if (v) {
                float4 es = *reinterpret_cast<const float4*>(&esrc[s * NHEAD]);
                lgc[c].x = leaky(es.x + ed.x);
                lgc[c].y = leaky(es.y + ed.y);
                lgc[c].z = leaky(es.z + ed.z);
                lgc[c].w = leaky(es.w + ed.w);
            }
            mx.x = fmaxf(mx.x, lgc[c].x);
            mx.y = fmaxf(mx.y, lgc[c].y);
            mx.z = fmaxf(mx.z, lgc[c].z);
            mx.w = fmaxf(mx.w, lgc[c].w);
        }
    }
    for (int i = s0 + 64 + t; i < s1; i += 16) {
        int e = eidx[i];
        int s = (e < E) ? ei[e] : (e - E);
        float4 es = *reinterpret_cast<const float4*>(&esrc[s * NHEAD]);
        mx.x = fmaxf(mx.x, leaky(es.x + ed.x));
        mx.y = fmaxf(mx.y, leaky(es.y + ed.y));
        mx.z = fmaxf(mx.z, leaky(es.z + ed.z));
        mx.w = fmaxf(mx.w, leaky(es.w + ed.w));
    }
#pragma unroll
    for (int off = 1; off < 16; off <<= 1) {
        mx.x = fmaxf(mx.x, __shfl_xor(mx.x, off, 64));
        mx.y = fmaxf(mx.y, __shfl_xor(mx.y, off, 64));
        mx.z = fmaxf(mx.z, __shfl_xor(mx.z, off, 64));
        mx.w = fmaxf(mx.w, __shfl_xor(mx.w, off, 64));
    }
    float4 exc[4];
    float4 sm = make_float4(0.f, 0.f, 0.f, 0.f);
#pragma unroll
    for (int c = 0; c < 4; ++c) {
        exc[c] = make_float4(0.f, 0.f, 0.f, 0.f);
        if (c < nch) {
            exc[c].x = __expf(lgc[c].x - mx.x);
            exc[c].y = __expf(lgc[c].y - mx.y);
            exc[c].z = __expf(lgc[c].z - mx.z);
            exc[c].w = __expf(lgc[c].w - mx.w);
            sm.x += exc[c].x; sm.y += exc[c].y; sm.z += exc[c].z; sm.w += exc[c].w;
        }
    }
    for (int i = s0 + 64 + t; i < s1; i += 16) {
        int e = eidx[i];
        int s = (e < E) ? ei[e] : (e - E);
        float4 es = *reinterpret_cast<const float4*>(&esrc[s * NHEAD]);
        sm.x += __expf(leaky(es.x + ed.x) - mx.x);
        sm.y += __expf(leaky(es.y + ed.y) - mx.y);
        sm.z += __expf(leaky(es.z + ed.z) - mx.z);
        sm.w += __expf(leaky(es.w + ed.w) - mx.w);
    }
#pragma unroll
    for (int off = 1; off < 16; off <<= 1) {
        sm.x += __shfl_xor(sm.x, off, 64);
        sm.y += __shfl_xor(sm.y, off, 64);
        sm.z += __shfl_xor(sm.z, off, 64);
        sm.w += __shfl_xor(sm.w, off, 64);
    }
    float4 inv = make_float4(1.f / sm.x, 1.f / sm.y, 1.f / sm.z, 1.f / sm.w);
#pragma unroll
    for (int c = 0; c < 4; ++c) {
        if (c < nch) {
            float4 al4;
            al4.x = exc[c].x * inv.x; al4.y = exc[c].y * inv.y;
            al4.z = exc[c].z * inv.z; al4.w = exc[c].w * inv.w;
            int i = s0 + c * 16 + t;
            if (i < s1) *reinterpret_cast<float4*>(&alpha[(size_t)ec[c] * NHEAD]) = al4;
            int eo = c * 16 + t;
            *reinterpret_cast<float4*>(&aT[nidx][eo][0]) = al4;
            sArr[nidx][eo] = sc[c];
        }
    }
    for (int i = s0 + 64 + t; i < s1; i += 16) {
        int e = eidx[i];
        int s = (e < E) ? ei[e] : (e - E);
        float4 es = *reinterpret_cast<const float4*>(&esrc[s * NHEAD]);
        float4 av;
        av.x = __expf(leaky(es.x + ed.x) - mx.x) * inv.x;
        av.y = __expf(leaky(es.y + ed.y) - mx.y) * inv.y;
        av.z = __expf(leaky(es.z + ed.z) - mx.z) * inv.z;
        av.w = __expf(leaky(es.w + ed.w) - mx.w) * inv.w;
        *reinterpret_cast<float4*>(&alpha[(size_t)e * NHEAD]) = av;
    }
    if (__any(deg > 64)) __threadfence();

    asm volatile("s_waitcnt lgkmcnt(0)" ::: "memory");
    __builtin_amdgcn_sched_barrier(0);

    int half = lane >> 5;
    int q = lane & 31;
    int head = q >> 3;
    unsigned byteoff = (unsigned)q * 16u;
    const char* hb = (const char*)h;

    for (int g2 = 0; g2 < 4; ++g2) {
        int nl = wave * 4 + g2;
        int nd = nodeblk + nl;
        if (nd >= n) continue;
        int t0 = rowptr[nd], t1 = rowptr[nd + 1];
        int dg = t1 - t0;
        int m = dg < 64 ? dg : 64;
        int m8 = (m + 7) & ~7;
        const float* ap = &aT[nl][0][0] + head;
        const int* sp = &sArr[nl][0];
        float acc[8];
#pragma unroll
        for (int k = 0; k < 8; ++k) acc[k] = 0.f;
        for (int j = 0; j < m8; j += 8) {
            int jA = j + half, jB = j + 2 + half, jC = j + 4 + half, jD = j + 6 + half;
            int sA = sp[jA], sB = sp[jB], sC = sp[jC], sD = sp[jD];
            float aA = ap[jA * NHEAD], aB = ap[jB * NHEAD];
            float aC = ap[jC * NHEAD], aD = ap[jD * NHEAD];
            uint4 hA = *reinterpret_cast<const uint4*>(hb + (((unsigned)sA) << 9) + byteoff);
            uint4 hB = *reinterpret_cast<const uint4*>(hb + (((unsigned)sB) << 9) + byteoff);
            uint4 hC = *reinterpret_cast<const uint4*>(hb + (((unsigned)sC) << 9) + byteoff);
            uint4 hD = *reinterpret_cast<const uint4*>(hb + (((unsigned)sD) << 9) + byteoff);
            fma8(acc, hA, aA);
            fma8(acc, hB, aB);
            fma8(acc, hC, aC);
            fma8(acc, hD, aD);
        }
        if (dg > 64) {
            for (int i = t0 + 64; i < t1; ++i) {
                if (half == 0) {
                    int e = eidx[i];
                    int s = (e < E) ? ei[e] : (e - E);
                    float a = alpha[(size_t)e * NHEAD + head];
                    uint4 hv = *reinterpret_cast<const uint4*>(hb + (((unsigned)s) << 9) + byteoff);
                    fma8(acc, hv, a);
                }
            }
        }
#pragma unroll
        for (int k = 0; k < 8; ++k) {
            acc[k] += __shfl_xor(acc[k], 32, 64);
            acc[k] += __shfl_xor(acc[k], 8, 64);
            acc[k] += __shfl_xor(acc[k], 16, 64);
        }
        if (half == 0 && q < 8) {
            float* op = xout + (size_t)nd * CDIM + q * 8;
            float4 r0, r1;
            r0.x = acc[0] * 0.25f + bias[q * 8 + 0];
            r0.y = acc[1] * 0.25f + bias[q * 8 + 1];
            r0.z = acc[2] * 0.25f + bias[q * 8 + 2];
            r0.w = acc[3] * 0.25f + bias[q * 8 + 3];
            r1.x = acc[4] * 0.25f + bias[q * 8 + 4];
            r1.y = acc[5] * 0.25f + bias[q * 8 + 5];
            r1.z = acc[6] * 0.25f + bias[q * 8 + 6];
            r1.w = acc[7] * 0.25f + bias[q * 8 + 7];
            *reinterpret_cast<float4*>(op)     = r0;
            *reinterpret_cast<float4*>(op + 4) = r1;
        }
    }
}

// ---------------------------------------------------------------- launch
extern "C" void kernel_launch(void* const* d_in, const int* in_sizes, int n_in,
                              void* d_out, int out_size, void* d_ws, size_t ws_size,
                              hipStream_t stream) {
    const float* x   = (const float*)d_in[0];
    const int*   ei  = (const int*)d_in[1];
    const float* W0  = (const float*)d_in[2];
    const float* as0 = (const float*)d_in[3];
    const float* ad0 = (const float*)d_in[4];
    const float* b0  = (const float*)d_in[5];
    const float* W1  = (const float*)d_in[6];
    const float* as1 = (const float*)d_in[7];
    const float* ad1 = (const float*)d_in[8];
    const float* b1  = (const float*)d_in[9];
    const float* W2  = (const float*)d_in[10];
    const float* as2 = (const float*)d_in[11];
    const float* ad2 = (const float*)d_in[12];
    const float* b2  = (const float*)d_in[13];

    const int N  = in_sizes[0] / 128;
    const int E  = in_sizes[1] / 2;
    const int Ep = E + N;

    float* out = (float*)d_out;
    float* a0  = out + (size_t)N * CDIM;
    float* a1  = a0 + (size_t)Ep * NHEAD;
    float* a2  = a1 + (size_t)Ep * NHEAD;

    char* wp = (char*)d_ws;
    auto carve = [&](size_t bytes) {
        char* p = wp;
        wp += (bytes + 255) & ~(size_t)255;
        return (void*)p;
    };
    unsigned short* hbufA = (unsigned short*)carve((size_t)N * HCOLS * 2);   // bf16
    unsigned short* hbufB = (unsigned short*)carve((size_t)N * HCOLS * 2);   // bf16
    float* esrcA  = (float*)carve((size_t)N * NHEAD * 4);
    float* edstA  = (float*)carve((size_t)N * NHEAD * 4);
    float* esrcB  = (float*)carve((size_t)N * NHEAD * 4);
    float* edstB  = (float*)carve((size_t)N * NHEAD * 4);
    int*   deg    = (int*)carve((size_t)N * 4);
    int*   rowptr = (int*)carve((size_t)(N + 1) * 4);
    int*   cursor = (int*)carve((size_t)N * 4);
    int*   eidx   = (int*)carve((size_t)Ep * 4);
    unsigned short* Wt0 = (unsigned short*)carve((size_t)HCOLS * 128 * 2);
    unsigned short* Wt1 = (unsigned short*)carve((size_t)HCOLS * HCOLS * 2);
    unsigned short* Wt2 = (unsigned short*)carve((size_t)HCOLS * HCOLS * 2);

    // prep: zero deg + W->bf16 transposed (single launch)
    int nzb = (N + 255) / 256;
    prep_kernel<<<nzb + 192, 256, 0, stream>>>(W0, W1, W2, Wt0, Wt1, Wt2, deg, N, nzb);
    deg_kernel<<<(Ep + 255) / 256, 256, 0, stream>>>(ei, deg, E, Ep);
    scan_kernel<<<1, 1024, 0, stream>>>(deg, rowptr, cursor, N);
    fill_kernel<<<(Ep + 255) / 256, 256, 0, stream>>>(ei, cursor, eidx, E, Ep);

    int gemm_grid  = (N + 31) / 32;
    int fused_grid = (N + 15) / 16;
    int mean_grid  = (N + 15) / 16;

    // ---- layer 0 GEMM (K = 128, fp32 source) -> h0 (A), es0/ed0 (A)
    gemm_kernel<128, true><<<gemm_grid, 256, 0, stream>>>(x, Wt0, hbufA, as0, ad0, esrcA, edstA, N);
    // ---- attn0 + gemm1 fused -> a0, h1 (B), es1/ed1 (B)
    attn_gemm_kernel<<<fused_grid, 256, 0, stream>>>(hbufA, esrcA, edstA, ei, rowptr, eidx,
                                                     b0, a0, Wt1, hbufB, as1, ad1, esrcB, edstB, N, E);
    // ---- attn1 + gemm2 fused -> a1, h2 (A), es2/ed2 (A)
    attn_gemm_kernel<<<fused_grid, 256, 0, stream>>>(hbufB, esrcB, edstB, ei, rowptr, eidx,
                                                     b1, a1, Wt2, hbufA, as2, ad2, esrcA, edstA, N, E);
    // ---- attn2 (head-mean) -> a2, out
    attn_mean_kernel<<<mean_grid, 256, 0, stream>>>(hbufA, esrcA, edstA, ei, rowptr, eidx,
                                                    b2, a2, out, N, E);
}